// Round 10
// baseline (644.846 us; speedup 1.0000x reference)
//
#include <hip/hip_runtime.h>
#include <hip/hip_fp16.h>

// ---------------------------------------------------------------------------
// GCN: 4 layers of  h' = A_hat_norm (h @ W) + b  on fixed graph, fp32.
// R3/R4: binned counting-sort CSR. R9-R12: gather widened to 32 rows in
//   flight, fp16 G, byte-offset col. agg = 69-71us, pinned at L2-fill
//   transaction rate (1.0 fills/cyc/XCD, G L3-resident).
// R13: coop mega-fusion 1358us CATASTROPHE. R14: LDS-staged GEMM, 555 best.
// R15: grid-stride agg REGRESSED (dispersed gather window). R16/R17: agg+W
//   epilogue fusion: +38us/dispatch VALU, abandoned.
// R18: fp16 Y handoff: WRITE halved, aggs/wall unchanged -> ledger now
//   PINS each gemm at ~65-70us regardless of K, staging, precision.
// R19: THE NETWORK IS LINEAR (no ReLU in reference!). S = D*Ahat*D commutes
//   with right-mult by W:
//     y = S^4 x (W0W1W2W3) + (S^3 1)c0' + (S^2 1)c1' + (S 1)c2' + 1 b3'
//   with c0=b0W1W2W3, c1=b1W2W3, c2=b2W3 (ALL b's are zero in this data).
//   => delete 3 of 4 gemms. Pipeline: CSR -> smallmats(Wc,c) ->
//   3x svec (4B-gathers from 400KB L2-resident table, ~5us each) ->
//   gemm0(x@Wc) -> agg x3 with dinv^2 epilogue (NO inter-layer gemm) ->
//   agg_final (+u*c bias terms + projection).
//   Predict: aggs ~70-71 (FETCH ~159MB), gemm0 <=70, svec ~5,
//   wall 579 -> ~390-420, absmax ~1e-4. If wall >=480: gemm time was
//   never in the gemm dispatches -> pivot to measurement.
// ---------------------------------------------------------------------------

#define FEAT 128
#define EMB 64
#define BINSHIFT 8
#define BINSIZE 256
#define NBIN 391          // ceil(100000/256)
#define CHUNK 8192

// ---------------- CSR build (unchanged, proven) ----------------

__global__ __launch_bounds__(256) void bin_count_k(
    const int* __restrict__ dst, int* __restrict__ bincnt, int E) {
    __shared__ int hist[NBIN];
    int t = threadIdx.x;
    int base = blockIdx.x * CHUNK;
    int end = min(base + CHUNK, E);
    for (int i = t; i < NBIN; i += 256) hist[i] = 0;
    __syncthreads();
    for (int e = base + t; e < end; e += 256)
        atomicAdd(&hist[dst[e] >> BINSHIFT], 1);
    __syncthreads();
    for (int b = t; b < NBIN; b += 256) {
        int c = hist[b];
        if (c > 0) atomicAdd(&bincnt[b], c);
    }
}

__global__ void binscan_k(const int* __restrict__ bincnt, int* __restrict__ binptr,
                          int* __restrict__ bincur, int nbin, int E) {
    __shared__ int s[512];
    int t = threadIdx.x;
    int v = (t < nbin) ? bincnt[t] : 0;
    s[t] = v;
    __syncthreads();
    for (int off = 1; off < 512; off <<= 1) {
        int tv = (t >= off) ? s[t - off] : 0;
        __syncthreads();
        s[t] += tv;
        __syncthreads();
    }
    if (t < nbin) {
        int excl = s[t] - v;
        binptr[t] = excl;
        bincur[t] = excl;
    }
    if (t == 0) binptr[nbin] = E;
}

__global__ __launch_bounds__(256) void bin_edges_k(
    const int* __restrict__ src, const int* __restrict__ dst,
    int* __restrict__ bincur, int* __restrict__ ebuf, int E) {
    __shared__ int hist[NBIN];
    __shared__ int lcur[NBIN];
    int t = threadIdx.x;
    int base = blockIdx.x * CHUNK;
    int end = min(base + CHUNK, E);
    for (int i = t; i < NBIN; i += 256) hist[i] = 0;
    __syncthreads();
    for (int e = base + t; e < end; e += 256)
        atomicAdd(&hist[dst[e] >> BINSHIFT], 1);
    __syncthreads();
    for (int b = t; b < NBIN; b += 256) {
        int c = hist[b];
        lcur[b] = (c > 0) ? atomicAdd(&bincur[b], c) : 0;
    }
    __syncthreads();
    for (int e = base + t; e < end; e += 256) {
        int d = dst[e];
        int bin = d >> BINSHIFT;
        int r = atomicAdd(&lcur[bin], 1);
        ebuf[r] = src[e] | ((d & (BINSIZE - 1)) << 24);
    }
}

__global__ __launch_bounds__(256) void build_csr_k(
    const int* __restrict__ ebuf, const int* __restrict__ binptr,
    int* __restrict__ rowptr, float* __restrict__ dinv,
    int* __restrict__ col, int N, int E, int nbin) {
    __shared__ int lcnt[BINSIZE];
    __shared__ int lscan[BINSIZE];
    __shared__ int lcur[BINSIZE];
    int b = blockIdx.x;
    int t = threadIdx.x;
    int n0 = b << BINSHIFT;
    int e0 = binptr[b];
    int e1 = binptr[b + 1];

    lcnt[t] = 0;
    __syncthreads();
    for (int i = e0 + t; i < e1; i += 256)
        atomicAdd(&lcnt[((unsigned)ebuf[i]) >> 24], 1);
    __syncthreads();

    int v = lcnt[t];
    lscan[t] = v;
    __syncthreads();
    for (int off = 1; off < 256; off <<= 1) {
        int tv = (t >= off) ? lscan[t - off] : 0;
        __syncthreads();
        lscan[t] += tv;
        __syncthreads();
    }
    int excl = e0 + lscan[t] - v;
    lcur[t] = excl;
    if (n0 + t < N) {
        rowptr[n0 + t] = excl;
        dinv[n0 + t] = 1.0f / sqrtf((float)(v + 1));
    }
    if (b == nbin - 1 && t == 0) rowptr[N] = E;
    __syncthreads();

    for (int i = e0 + t; i < e1; i += 256) {
        int w = ebuf[i];
        int dl = ((unsigned)w) >> 24;
        int p = atomicAdd(&lcur[dl], 1);
        col[p] = (w & 0xFFFFFF) << 7;   // byte offset into fp16 G (row = 128B)
    }
}

// ---------------- Small matrices: Wc = W0W1W2W3, c vectors ----------------
// One block. T1 = W2*W3, T2 = W1*T1, Wc = W0*T2 (128x64).
// c0 = b0*T2, c1 = b1*T1, c2 = b2*W3 (rows of 64).

__global__ __launch_bounds__(256) void smallmats_k(
    const float* __restrict__ W0, const float* __restrict__ W1,
    const float* __restrict__ W2, const float* __restrict__ W3,
    const float* __restrict__ b0, const float* __restrict__ b1,
    const float* __restrict__ b2,
    float* __restrict__ Wc, float* __restrict__ cbuf) {
    __shared__ float T1[64 * 65];
    __shared__ float T2[64 * 65];
    int t = threadIdx.x;
    for (int idx = t; idx < 4096; idx += 256) {
        int i = idx >> 6, j = idx & 63;
        float s = 0.f;
        for (int k = 0; k < 64; k++) s = fmaf(W2[i * 64 + k], W3[k * 64 + j], s);
        T1[i * 65 + j] = s;
    }
    __syncthreads();
    for (int idx = t; idx < 4096; idx += 256) {
        int i = idx >> 6, j = idx & 63;
        float s = 0.f;
        for (int k = 0; k < 64; k++) s = fmaf(W1[i * 64 + k], T1[k * 65 + j], s);
        T2[i * 65 + j] = s;
    }
    __syncthreads();
    for (int idx = t; idx < 8192; idx += 256) {
        int i = idx >> 6, j = idx & 63;
        float s = 0.f;
        for (int k = 0; k < 64; k++) s = fmaf(W0[i * 64 + k], T2[k * 65 + j], s);
        Wc[idx] = s;
    }
    if (t < 64) {
        float s0 = 0.f, s1 = 0.f, s2 = 0.f;
        for (int k = 0; k < 64; k++) {
            s0 = fmaf(b0[k], T2[k * 65 + t], s0);
            s1 = fmaf(b1[k], T1[k * 65 + t], s1);
            s2 = fmaf(b2[k], W3[k * 64 + t], s2);
        }
        cbuf[t] = s0; cbuf[64 + t] = s1; cbuf[128 + t] = s2;
    }
}

// ---------------- svec: one S application to a scalar field ----------------
// in: w = D * v (pre-scaled). out: u = S v = D*Ahat*w ; wnext = D*u.
// Gathers are 4B from a 400KB table -> L2-resident -> fast.

__global__ __launch_bounds__(256) void svec_k(
    const float* __restrict__ w, const float* __restrict__ dinv,
    const int* __restrict__ rowptr, const int* __restrict__ coff,
    float* __restrict__ u, float* __restrict__ wnext, int N) {
    int i = blockIdx.x * 256 + threadIdx.x;
    if (i >= N) return;
    int s = rowptr[i], e = rowptr[i + 1];
    float acc = w[i];                       // self loop
    for (int j = s; j < e; j++)
        acc += w[((unsigned)coff[j]) >> 7]; // coff = src<<7
    float d = dinv[i];
    u[i] = d * acc;
    wnext[i] = d * d * acc;
}

// ---------------- GEMM (the ONLY one): G0 = (x @ Wc) * dinv, fp16 out ----
// Proven R15 form: tile-stride, W staged once per block, LDS A-tile.

#define AKP 68   // padded A-tile row stride in floats (BK=64 + 4)

template <int K>
__global__ __launch_bounds__(256, 4) void gemm_scale_k(
    const float* __restrict__ H, const float* __restrict__ W,
    const float* __restrict__ dinv, __half* __restrict__ G, int N, int ntile) {
    __shared__ float Ws[K * EMB];
    __shared__ float As[64 * AKP];
    int t = threadIdx.x;

    for (int i = t * 4; i < K * EMB; i += 1024)
        *(float4*)(Ws + i) = *(const float4*)(W + i);

    int tc = t & 15;
    int tr = t >> 4;
    int j0 = tc * 4;

    for (int tile = blockIdx.x; tile < ntile; tile += gridDim.x) {
        int r0blk = tile * 64;
        float acc[4][4] = {{0.f}};

        for (int k0 = 0; k0 < K; k0 += 64) {
            __syncthreads();
#pragma unroll
            for (int n = 0; n < 4; n++) {
                int idx = t + n * 256;
                int row = idx >> 4;
                int cg  = idx & 15;
                int r = r0blk + row;
                if (r >= N) r = N - 1;
                *(float4*)(As + row * AKP + cg * 4) =
                    *(const float4*)(H + (size_t)r * K + k0 + cg * 4);
            }
            __syncthreads();

#pragma unroll 2
            for (int k = 0; k < 64; k += 4) {
                float4 a[4];
#pragma unroll
                for (int i = 0; i < 4; i++)
                    a[i] = *(const float4*)(As + (tr * 4 + i) * AKP + k);
#pragma unroll
                for (int kk = 0; kk < 4; kk++) {
                    float4 wv = *(const float4*)(Ws + (k0 + k + kk) * EMB + j0);
#pragma unroll
                    for (int i = 0; i < 4; i++) {
                        float av = (kk == 0) ? a[i].x : (kk == 1) ? a[i].y
                                 : (kk == 2) ? a[i].z : a[i].w;
                        acc[i][0] = fmaf(av, wv.x, acc[i][0]);
                        acc[i][1] = fmaf(av, wv.y, acc[i][1]);
                        acc[i][2] = fmaf(av, wv.z, acc[i][2]);
                        acc[i][3] = fmaf(av, wv.w, acc[i][3]);
                    }
                }
            }
        }

        int r0 = r0blk + tr * 4;
#pragma unroll
        for (int i = 0; i < 4; i++) {
            if (r0 + i < N) {
                float s = dinv[r0 + i];
                union { __half2 h2[2]; float2 f2; } o;
                o.h2[0] = __floats2half2_rn(acc[i][0] * s, acc[i][1] * s);
                o.h2[1] = __floats2half2_rn(acc[i][2] * s, acc[i][3] * s);
                *(float2*)(G + (size_t)(r0 + i) * EMB + j0) = o.f2;
            }
        }
    }
}

// ---------------- Aggregation core (R12, proven) ----------------

__device__ __forceinline__ void h8_acc(float (&a)[8], float4 raw) {
    union { float4 f4; __half2 h2[4]; } u;
    u.f4 = raw;
    float2 p0 = __half22float2(u.h2[0]);
    float2 p1 = __half22float2(u.h2[1]);
    float2 p2 = __half22float2(u.h2[2]);
    float2 p3 = __half22float2(u.h2[3]);
    a[0] += p0.x; a[1] += p0.y; a[2] += p1.x; a[3] += p1.y;
    a[4] += p2.x; a[5] += p2.y; a[6] += p3.x; a[7] += p3.y;
}

__device__ __forceinline__ void agg_node8(const __half* __restrict__ G,
                                          const int* __restrict__ coff,
                                          int s, int e, int selfoff,
                                          int grp, int f8, float (&r)[8]) {
    const char* Gb = (const char*)G + f8 * 16;
    float a0[8] = {0.f, 0.f, 0.f, 0.f, 0.f, 0.f, 0.f, 0.f};
    float a1[8] = {0.f, 0.f, 0.f, 0.f, 0.f, 0.f, 0.f, 0.f};
    float a2[8] = {0.f, 0.f, 0.f, 0.f, 0.f, 0.f, 0.f, 0.f};
    float a3[8] = {0.f, 0.f, 0.f, 0.f, 0.f, 0.f, 0.f, 0.f};
    if (grp == 0) h8_acc(a0, *(const float4*)(Gb + selfoff));  // self loop

    int i = s;
    if (i + 32 <= e) {
        int c0 = coff[i + grp];
        int c1 = coff[i + 8 + grp];
        int c2 = coff[i + 16 + grp];
        int c3 = coff[i + 24 + grp];
        while (true) {
            float4 g0 = *(const float4*)(Gb + (size_t)(unsigned)c0);
            float4 g1 = *(const float4*)(Gb + (size_t)(unsigned)c1);
            float4 g2 = *(const float4*)(Gb + (size_t)(unsigned)c2);
            float4 g3 = *(const float4*)(Gb + (size_t)(unsigned)c3);
            i += 32;
            bool more = (i + 32 <= e);
            if (more) {
                c0 = coff[i + grp];
                c1 = coff[i + 8 + grp];
                c2 = coff[i + 16 + grp];
                c3 = coff[i + 24 + grp];
            }
            h8_acc(a0, g0);
            h8_acc(a1, g1);
            h8_acc(a2, g2);
            h8_acc(a3, g3);
            if (!more) break;
        }
    }
    for (; i + 8 <= e; i += 8) {
        float4 g = *(const float4*)(Gb + (size_t)(unsigned)coff[i + grp]);
        h8_acc(a1, g);
    }
    if (grp < e - i) {
        float4 g = *(const float4*)(Gb + (size_t)(unsigned)coff[i + grp]);
        h8_acc(a2, g);
    }

#pragma unroll
    for (int k = 0; k < 8; k++) {
        float v = (a0[k] + a1[k]) + (a2[k] + a3[k]);
        v += __shfl_xor(v, 8, 64);
        v += __shfl_xor(v, 16, 64);
        v += __shfl_xor(v, 32, 64);
        r[k] = v;
    }
}

// Middle S-applications: Gout = D^2 * Ahat(G) as fp16 (row 128B).
__global__ __launch_bounds__(256) void agg_mid_k(
    const __half* __restrict__ G, const float* __restrict__ dinv,
    const int* __restrict__ rowptr, const int* __restrict__ coff,
    __half* __restrict__ Gout, int N) {
    int gw = (blockIdx.x * 256 + threadIdx.x) >> 6;
    int lane = threadIdx.x & 63;
    if (gw >= N) return;
    gw = __builtin_amdgcn_readfirstlane(gw);
    int grp = lane >> 3;
    int f8 = lane & 7;
    int s = rowptr[gw], e = rowptr[gw + 1];
    float r[8];
    agg_node8(G, coff, s, e, gw << 7, grp, f8, r);
    if (grp == 0) {
        float d = dinv[gw];
        float dd = d * d;
        union { __half2 h2[4]; float4 f4; } o;
        o.h2[0] = __floats2half2_rn(r[0] * dd, r[1] * dd);
        o.h2[1] = __floats2half2_rn(r[2] * dd, r[3] * dd);
        o.h2[2] = __floats2half2_rn(r[4] * dd, r[5] * dd);
        o.h2[3] = __floats2half2_rn(r[6] * dd, r[7] * dd);
        *(float4*)((char*)Gout + ((size_t)gw << 7) + f8 * 16) = o.f4;
    }
}

// Final: y = D*Ahat(G3) + u2*c0 + u1*c1 + u0*c2 + b3; store Y fp32;
// Out = y @ Wout + bout.
__global__ __launch_bounds__(256) void agg_final_k(
    const __half* __restrict__ G, const float* __restrict__ dinv,
    const int* __restrict__ rowptr, const int* __restrict__ coff,
    const float* __restrict__ u0, const float* __restrict__ u1,
    const float* __restrict__ u2, const float* __restrict__ cbuf,
    const float* __restrict__ b3, const float* __restrict__ Wout,
    const float* __restrict__ bout, float* __restrict__ Y,
    float* __restrict__ Out, int N) {
    int gw = (blockIdx.x * 256 + threadIdx.x) >> 6;
    int lane = threadIdx.x & 63;
    if (gw >= N) return;
    gw = __builtin_amdgcn_readfirstlane(gw);
    int grp = lane >> 3;
    int f8 = lane & 7;
    int s = rowptr[gw], e = rowptr[gw + 1];
    float r[8];
    agg_node8(G, coff, s, e, gw << 7, grp, f8, r);
    float d = dinv[gw];
    float u0v = u0[gw], u1v = u1[gw], u2v = u2[gw];
    const float* c0 = cbuf;
    const float* c1 = cbuf + 64;
    const float* c2 = cbuf + 128;
    float v[8];
#pragma unroll
    for (int half = 0; half < 2; half++) {
        int o4 = f8 * 8 + half * 4;
        float4 c0v = *(const float4*)(c0 + o4);
        float4 c1v = *(const float4*)(c1 + o4);
        float4 c2v = *(const float4*)(c2 + o4);
        float4 b3v = *(const float4*)(b3 + o4);
        v[half * 4 + 0] = r[half * 4 + 0] * d + u2v * c0v.x + u1v * c1v.x + u0v * c2v.x + b3v.x;
        v[half * 4 + 1] = r[half * 4 + 1] * d + u2v * c0v.y + u1v * c1v.y + u0v * c2v.y + b3v.y;
        v[half * 4 + 2] = r[half * 4 + 2] * d + u2v * c0v.z + u1v * c1v.z + u0v * c2v.z + b3v.z;
        v[half * 4 + 3] = r[half * 4 + 3] * d + u2v * c0v.w + u1v * c1v.w + u0v * c2v.w + b3v.w;
    }
    if (grp == 0) {
        float* o = Y + (size_t)gw * EMB + f8 * 8;
        *(float4*)o = make_float4(v[0], v[1], v[2], v[3]);
        *(float4*)(o + 4) = make_float4(v[4], v[5], v[6], v[7]);
    }
    float4 w0v = *(const float4*)(Wout + f8 * 8);
    float4 w1v = *(const float4*)(Wout + f8 * 8 + 4);
    float p = v[0] * w0v.x + v[1] * w0v.y + v[2] * w0v.z + v[3] * w0v.w +
              v[4] * w1v.x + v[5] * w1v.y + v[6] * w1v.z + v[7] * w1v.w;
    p += __shfl_xor(p, 1, 8);
    p += __shfl_xor(p, 2, 8);
    p += __shfl_xor(p, 4, 8);
    if (lane == 0) Out[gw] = p + bout[0];
}

// ---------------- launch ----------------

extern "C" void kernel_launch(void* const* d_in, const int* in_sizes, int n_in,
                              void* d_out, int out_size, void* d_ws, size_t ws_size,
                              hipStream_t stream) {
    const float* x    = (const float*)d_in[0];
    const int*   ei   = (const int*)d_in[1];
    const float* W0   = (const float*)d_in[3];
    const float* b0   = (const float*)d_in[4];
    const float* W1   = (const float*)d_in[5];
    const float* b1   = (const float*)d_in[6];
    const float* W2   = (const float*)d_in[7];
    const float* b2   = (const float*)d_in[8];
    const float* W3   = (const float*)d_in[9];
    const float* b3   = (const float*)d_in[10];
    const float* Wout = (const float*)d_in[11];
    const float* bout = (const float*)d_in[12];

    const int N = in_sizes[0] / FEAT;      // 100000
    const int E = in_sizes[1] / 2;         // 3200000
    const int* srcp = ei;                  // edge_index[0]
    const int* dstp = ei + E;              // edge_index[1]
    const int nbin = (N + BINSIZE - 1) / BINSIZE;   // 391

    // workspace layout (floats; regions padded to 64 for float4 alignment)
    const int NP = ((N + 64) + 63) / 64 * 64;   // holds N+1
    float* dinv  = (float*)d_ws;
    int* rowptr  = (int*)(dinv + NP);
    int* bincnt  = rowptr + NP;
    int* binptr  = bincnt + 1024;
    int* bincur  = binptr + 1024;
    int* col     = bincur + 1024;
    float* u0    = (float*)(col + ((E + 63) / 64) * 64);
    float* u1    = u0 + NP;
    float* u2    = u1 + NP;
    float* Wc    = u2 + NP;                // 128x64 = 8192 floats
    float* cbuf  = Wc + 8192;              // 192 floats (c0,c1,c2)
    float* gbase = cbuf + 256;
    int* ebuf    = (int*)gbase;            // aliased: dead before gemm0
    __half* Gbuf0 = (__half*)gbase;        // fp16 G ping (12.8MB)
    __half* Gbuf1 = Gbuf0 + (size_t)N * EMB;  // fp16 G pong (12.8MB)
    float* wa    = (float*)(Gbuf1 + (size_t)N * EMB);  // svec scratch
    float* wb    = wa + NP;                // (dead before gemm0? no --
                                           // placed after G bufs, persistent)

    float* Out = (float*)d_out;
    float* Y   = Out + N;

    const int ntile = (N + 63) / 64;               // 1563
    const int gemm_grid = (ntile < 768) ? ntile : 768;
    const int agg_blocks = (N + 3) / 4;            // 25000 exact-grid
    const int svec_blocks = (N + 255) / 256;       // 391
    const int nchunk = (E + CHUNK - 1) / CHUNK;

    // --- CSR build ---
    hipMemsetAsync(bincnt, 0, 1024 * sizeof(int), stream);
    bin_count_k<<<nchunk, 256, 0, stream>>>(dstp, bincnt, E);
    binscan_k<<<1, 512, 0, stream>>>(bincnt, binptr, bincur, nbin, E);
    bin_edges_k<<<nchunk, 256, 0, stream>>>(srcp, dstp, bincur, ebuf, E);
    build_csr_k<<<nbin, 256, 0, stream>>>(ebuf, binptr, rowptr, dinv, col, N, E, nbin);

    // --- collapsed weights + bias-correction ingredients ---
    smallmats_k<<<1, 256, 0, stream>>>(W0, W1, W2, W3, b0, b1, b2, Wc, cbuf);
    // u0 = S*1, u1 = S^2*1, u2 = S^3*1  (w0 = D*1 = dinv)
    svec_k<<<svec_blocks, 256, 0, stream>>>(dinv, dinv, rowptr, col, u0, wa, N);
    svec_k<<<svec_blocks, 256, 0, stream>>>(wa, dinv, rowptr, col, u1, wb, N);
    svec_k<<<svec_blocks, 256, 0, stream>>>(wb, dinv, rowptr, col, u2, wa, N);

    // --- the single GEMM: G0 = D * (x @ Wc) ---
    gemm_scale_k<FEAT><<<gemm_grid, 256, 0, stream>>>(x, Wc, dinv, Gbuf0, N, ntile);
    // --- S applications (no inter-layer gemm: epilogue is *dinv^2) ---
    agg_mid_k<<<agg_blocks, 256, 0, stream>>>(Gbuf0, dinv, rowptr, col, Gbuf1, N);
    agg_mid_k<<<agg_blocks, 256, 0, stream>>>(Gbuf1, dinv, rowptr, col, Gbuf0, N);
    agg_mid_k<<<agg_blocks, 256, 0, stream>>>(Gbuf0, dinv, rowptr, col, Gbuf1, N);
    // --- final S + bias terms + output projection ---
    agg_final_k<<<agg_blocks, 256, 0, stream>>>(Gbuf1, dinv, rowptr, col,
                                                u0, u1, u2, cbuf, b3, Wout, bout,
                                                Y, Out, N);
}

// Round 11
// 633.272 us; speedup vs baseline: 1.0183x; 1.0183x over previous
//
#include <hip/hip_runtime.h>
#include <hip/hip_fp16.h>

// ---------------------------------------------------------------------------
// GCN: 4 layers of  h' = A_hat_norm (h @ W) + b  on fixed graph, fp32.
// R3/R4: binned counting-sort CSR. R9-R12: gather widened to 32 rows in
//   flight, fp16 G, byte-offset col. agg = 69-79us, pinned at L2-fill rate.
// R13: coop mega-fusion CATASTROPHE. R14: LDS-staged GEMM split: 555 best.
// R15: grid-stride agg REGRESSED. R16/R17: agg+W fusion abandoned.
// R18: fp16 Y handoff: neutral. Ledger pins every gemm at ~65us.
// R19: LINEAR-NETWORK COLLAPSE (no ReLU): y = S^4 x Wc + bias-terms via
//   S^k 1 vectors. Deleted 3 gemms. absmax UNCHANGED (6.1e-5) -- math
//   right -- but wall 579->645! Ledger: max 435us of kernels vs 645 wall;
//   ~210us invisible. Cross-round pattern: ledgers close ONLY when huge
//   25000-wg aggs alternate with medium kernels (R12/R14/R18 gap 20-30);
//   consecutive huge->huge dependent dispatches cost ~50us/boundary
//   beyond reported durs (R16/17: 47-51, R19: 50-60).
// R20: pure launch-order A/B, zero kernel-body changes: interleave the
//   small kernels between the huge aggs:
//   CSR -> gemm0 -> svec1 -> mid1 -> svec2 -> mid2 -> svec3 -> mid3 ->
//   smallmats -> final.
//   Predict: per-dispatch counters unchanged; wall 645 -> ~450-490 if the
//   boundary theory holds; ~640 if not (then revert to R14 structure).
// ---------------------------------------------------------------------------

#define FEAT 128
#define EMB 64
#define BINSHIFT 8
#define BINSIZE 256
#define NBIN 391          // ceil(100000/256)
#define CHUNK 8192

// ---------------- CSR build (unchanged, proven) ----------------

__global__ __launch_bounds__(256) void bin_count_k(
    const int* __restrict__ dst, int* __restrict__ bincnt, int E) {
    __shared__ int hist[NBIN];
    int t = threadIdx.x;
    int base = blockIdx.x * CHUNK;
    int end = min(base + CHUNK, E);
    for (int i = t; i < NBIN; i += 256) hist[i] = 0;
    __syncthreads();
    for (int e = base + t; e < end; e += 256)
        atomicAdd(&hist[dst[e] >> BINSHIFT], 1);
    __syncthreads();
    for (int b = t; b < NBIN; b += 256) {
        int c = hist[b];
        if (c > 0) atomicAdd(&bincnt[b], c);
    }
}

__global__ void binscan_k(const int* __restrict__ bincnt, int* __restrict__ binptr,
                          int* __restrict__ bincur, int nbin, int E) {
    __shared__ int s[512];
    int t = threadIdx.x;
    int v = (t < nbin) ? bincnt[t] : 0;
    s[t] = v;
    __syncthreads();
    for (int off = 1; off < 512; off <<= 1) {
        int tv = (t >= off) ? s[t - off] : 0;
        __syncthreads();
        s[t] += tv;
        __syncthreads();
    }
    if (t < nbin) {
        int excl = s[t] - v;
        binptr[t] = excl;
        bincur[t] = excl;
    }
    if (t == 0) binptr[nbin] = E;
}

__global__ __launch_bounds__(256) void bin_edges_k(
    const int* __restrict__ src, const int* __restrict__ dst,
    int* __restrict__ bincur, int* __restrict__ ebuf, int E) {
    __shared__ int hist[NBIN];
    __shared__ int lcur[NBIN];
    int t = threadIdx.x;
    int base = blockIdx.x * CHUNK;
    int end = min(base + CHUNK, E);
    for (int i = t; i < NBIN; i += 256) hist[i] = 0;
    __syncthreads();
    for (int e = base + t; e < end; e += 256)
        atomicAdd(&hist[dst[e] >> BINSHIFT], 1);
    __syncthreads();
    for (int b = t; b < NBIN; b += 256) {
        int c = hist[b];
        lcur[b] = (c > 0) ? atomicAdd(&bincur[b], c) : 0;
    }
    __syncthreads();
    for (int e = base + t; e < end; e += 256) {
        int d = dst[e];
        int bin = d >> BINSHIFT;
        int r = atomicAdd(&lcur[bin], 1);
        ebuf[r] = src[e] | ((d & (BINSIZE - 1)) << 24);
    }
}

__global__ __launch_bounds__(256) void build_csr_k(
    const int* __restrict__ ebuf, const int* __restrict__ binptr,
    int* __restrict__ rowptr, float* __restrict__ dinv,
    int* __restrict__ col, int N, int E, int nbin) {
    __shared__ int lcnt[BINSIZE];
    __shared__ int lscan[BINSIZE];
    __shared__ int lcur[BINSIZE];
    int b = blockIdx.x;
    int t = threadIdx.x;
    int n0 = b << BINSHIFT;
    int e0 = binptr[b];
    int e1 = binptr[b + 1];

    lcnt[t] = 0;
    __syncthreads();
    for (int i = e0 + t; i < e1; i += 256)
        atomicAdd(&lcnt[((unsigned)ebuf[i]) >> 24], 1);
    __syncthreads();

    int v = lcnt[t];
    lscan[t] = v;
    __syncthreads();
    for (int off = 1; off < 256; off <<= 1) {
        int tv = (t >= off) ? lscan[t - off] : 0;
        __syncthreads();
        lscan[t] += tv;
        __syncthreads();
    }
    int excl = e0 + lscan[t] - v;
    lcur[t] = excl;
    if (n0 + t < N) {
        rowptr[n0 + t] = excl;
        dinv[n0 + t] = 1.0f / sqrtf((float)(v + 1));
    }
    if (b == nbin - 1 && t == 0) rowptr[N] = E;
    __syncthreads();

    for (int i = e0 + t; i < e1; i += 256) {
        int w = ebuf[i];
        int dl = ((unsigned)w) >> 24;
        int p = atomicAdd(&lcur[dl], 1);
        col[p] = (w & 0xFFFFFF) << 7;   // byte offset into fp16 G (row = 128B)
    }
}

// ---------------- Small matrices: Wc = W0W1W2W3, c vectors ----------------

__global__ __launch_bounds__(256) void smallmats_k(
    const float* __restrict__ W0, const float* __restrict__ W1,
    const float* __restrict__ W2, const float* __restrict__ W3,
    const float* __restrict__ b0, const float* __restrict__ b1,
    const float* __restrict__ b2,
    float* __restrict__ Wc, float* __restrict__ cbuf) {
    __shared__ float T1[64 * 65];
    __shared__ float T2[64 * 65];
    int t = threadIdx.x;
    for (int idx = t; idx < 4096; idx += 256) {
        int i = idx >> 6, j = idx & 63;
        float s = 0.f;
        for (int k = 0; k < 64; k++) s = fmaf(W2[i * 64 + k], W3[k * 64 + j], s);
        T1[i * 65 + j] = s;
    }
    __syncthreads();
    for (int idx = t; idx < 4096; idx += 256) {
        int i = idx >> 6, j = idx & 63;
        float s = 0.f;
        for (int k = 0; k < 64; k++) s = fmaf(W1[i * 64 + k], T1[k * 65 + j], s);
        T2[i * 65 + j] = s;
    }
    __syncthreads();
    for (int idx = t; idx < 8192; idx += 256) {
        int i = idx >> 6, j = idx & 63;
        float s = 0.f;
        for (int k = 0; k < 64; k++) s = fmaf(W0[i * 64 + k], T2[k * 65 + j], s);
        Wc[idx] = s;
    }
    if (t < 64) {
        float s0 = 0.f, s1 = 0.f, s2 = 0.f;
        for (int k = 0; k < 64; k++) {
            s0 = fmaf(b0[k], T2[k * 65 + t], s0);
            s1 = fmaf(b1[k], T1[k * 65 + t], s1);
            s2 = fmaf(b2[k], W3[k * 64 + t], s2);
        }
        cbuf[t] = s0; cbuf[64 + t] = s1; cbuf[128 + t] = s2;
    }
}

// ---------------- svec: one S application to a scalar field ----------------

__global__ __launch_bounds__(256) void svec_k(
    const float* __restrict__ w, const float* __restrict__ dinv,
    const int* __restrict__ rowptr, const int* __restrict__ coff,
    float* __restrict__ u, float* __restrict__ wnext, int N) {
    int i = blockIdx.x * 256 + threadIdx.x;
    if (i >= N) return;
    int s = rowptr[i], e = rowptr[i + 1];
    float acc = w[i];                       // self loop
    for (int j = s; j < e; j++)
        acc += w[((unsigned)coff[j]) >> 7]; // coff = src<<7
    float d = dinv[i];
    u[i] = d * acc;
    wnext[i] = d * d * acc;
}

// ---------------- GEMM (the ONLY one): G0 = (x @ Wc) * dinv, fp16 out ----

#define AKP 68   // padded A-tile row stride in floats (BK=64 + 4)

template <int K>
__global__ __launch_bounds__(256, 4) void gemm_scale_k(
    const float* __restrict__ H, const float* __restrict__ W,
    const float* __restrict__ dinv, __half* __restrict__ G, int N, int ntile) {
    __shared__ float Ws[K * EMB];
    __shared__ float As[64 * AKP];
    int t = threadIdx.x;

    for (int i = t * 4; i < K * EMB; i += 1024)
        *(float4*)(Ws + i) = *(const float4*)(W + i);

    int tc = t & 15;
    int tr = t >> 4;
    int j0 = tc * 4;

    for (int tile = blockIdx.x; tile < ntile; tile += gridDim.x) {
        int r0blk = tile * 64;
        float acc[4][4] = {{0.f}};

        for (int k0 = 0; k0 < K; k0 += 64) {
            __syncthreads();
#pragma unroll
            for (int n = 0; n < 4; n++) {
                int idx = t + n * 256;
                int row = idx >> 4;
                int cg  = idx & 15;
                int r = r0blk + row;
                if (r >= N) r = N - 1;
                *(float4*)(As + row * AKP + cg * 4) =
                    *(const float4*)(H + (size_t)r * K + k0 + cg * 4);
            }
            __syncthreads();

#pragma unroll 2
            for (int k = 0; k < 64; k += 4) {
                float4 a[4];
#pragma unroll
                for (int i = 0; i < 4; i++)
                    a[i] = *(const float4*)(As + (tr * 4 + i) * AKP + k);
#pragma unroll
                for (int kk = 0; kk < 4; kk++) {
                    float4 wv = *(const float4*)(Ws + (k0 + k + kk) * EMB + j0);
#pragma unroll
                    for (int i = 0; i < 4; i++) {
                        float av = (kk == 0) ? a[i].x : (kk == 1) ? a[i].y
                                 : (kk == 2) ? a[i].z : a[i].w;
                        acc[i][0] = fmaf(av, wv.x, acc[i][0]);
                        acc[i][1] = fmaf(av, wv.y, acc[i][1]);
                        acc[i][2] = fmaf(av, wv.z, acc[i][2]);
                        acc[i][3] = fmaf(av, wv.w, acc[i][3]);
                    }
                }
            }
        }

        int r0 = r0blk + tr * 4;
#pragma unroll
        for (int i = 0; i < 4; i++) {
            if (r0 + i < N) {
                float s = dinv[r0 + i];
                union { __half2 h2[2]; float2 f2; } o;
                o.h2[0] = __floats2half2_rn(acc[i][0] * s, acc[i][1] * s);
                o.h2[1] = __floats2half2_rn(acc[i][2] * s, acc[i][3] * s);
                *(float2*)(G + (size_t)(r0 + i) * EMB + j0) = o.f2;
            }
        }
    }
}

// ---------------- Aggregation core (R12, proven) ----------------

__device__ __forceinline__ void h8_acc(float (&a)[8], float4 raw) {
    union { float4 f4; __half2 h2[4]; } u;
    u.f4 = raw;
    float2 p0 = __half22float2(u.h2[0]);
    float2 p1 = __half22float2(u.h2[1]);
    float2 p2 = __half22float2(u.h2[2]);
    float2 p3 = __half22float2(u.h2[3]);
    a[0] += p0.x; a[1] += p0.y; a[2] += p1.x; a[3] += p1.y;
    a[4] += p2.x; a[5] += p2.y; a[6] += p3.x; a[7] += p3.y;
}

__device__ __forceinline__ void agg_node8(const __half* __restrict__ G,
                                          const int* __restrict__ coff,
                                          int s, int e, int selfoff,
                                          int grp, int f8, float (&r)[8]) {
    const char* Gb = (const char*)G + f8 * 16;
    float a0[8] = {0.f, 0.f, 0.f, 0.f, 0.f, 0.f, 0.f, 0.f};
    float a1[8] = {0.f, 0.f, 0.f, 0.f, 0.f, 0.f, 0.f, 0.f};
    float a2[8] = {0.f, 0.f, 0.f, 0.f, 0.f, 0.f, 0.f, 0.f};
    float a3[8] = {0.f, 0.f, 0.f, 0.f, 0.f, 0.f, 0.f, 0.f};
    if (grp == 0) h8_acc(a0, *(const float4*)(Gb + selfoff));  // self loop

    int i = s;
    if (i + 32 <= e) {
        int c0 = coff[i + grp];
        int c1 = coff[i + 8 + grp];
        int c2 = coff[i + 16 + grp];
        int c3 = coff[i + 24 + grp];
        while (true) {
            float4 g0 = *(const float4*)(Gb + (size_t)(unsigned)c0);
            float4 g1 = *(const float4*)(Gb + (size_t)(unsigned)c1);
            float4 g2 = *(const float4*)(Gb + (size_t)(unsigned)c2);
            float4 g3 = *(const float4*)(Gb + (size_t)(unsigned)c3);
            i += 32;
            bool more = (i + 32 <= e);
            if (more) {
                c0 = coff[i + grp];
                c1 = coff[i + 8 + grp];
                c2 = coff[i + 16 + grp];
                c3 = coff[i + 24 + grp];
            }
            h8_acc(a0, g0);
            h8_acc(a1, g1);
            h8_acc(a2, g2);
            h8_acc(a3, g3);
            if (!more) break;
        }
    }
    for (; i + 8 <= e; i += 8) {
        float4 g = *(const float4*)(Gb + (size_t)(unsigned)coff[i + grp]);
        h8_acc(a1, g);
    }
    if (grp < e - i) {
        float4 g = *(const float4*)(Gb + (size_t)(unsigned)coff[i + grp]);
        h8_acc(a2, g);
    }

#pragma unroll
    for (int k = 0; k < 8; k++) {
        float v = (a0[k] + a1[k]) + (a2[k] + a3[k]);
        v += __shfl_xor(v, 8, 64);
        v += __shfl_xor(v, 16, 64);
        v += __shfl_xor(v, 32, 64);
        r[k] = v;
    }
}

// Middle S-applications: Gout = D^2 * Ahat(G) as fp16 (row 128B).
__global__ __launch_bounds__(256) void agg_mid_k(
    const __half* __restrict__ G, const float* __restrict__ dinv,
    const int* __restrict__ rowptr, const int* __restrict__ coff,
    __half* __restrict__ Gout, int N) {
    int gw = (blockIdx.x * 256 + threadIdx.x) >> 6;
    int lane = threadIdx.x & 63;
    if (gw >= N) return;
    gw = __builtin_amdgcn_readfirstlane(gw);
    int grp = lane >> 3;
    int f8 = lane & 7;
    int s = rowptr[gw], e = rowptr[gw + 1];
    float r[8];
    agg_node8(G, coff, s, e, gw << 7, grp, f8, r);
    if (grp == 0) {
        float d = dinv[gw];
        float dd = d * d;
        union { __half2 h2[4]; float4 f4; } o;
        o.h2[0] = __floats2half2_rn(r[0] * dd, r[1] * dd);
        o.h2[1] = __floats2half2_rn(r[2] * dd, r[3] * dd);
        o.h2[2] = __floats2half2_rn(r[4] * dd, r[5] * dd);
        o.h2[3] = __floats2half2_rn(r[6] * dd, r[7] * dd);
        *(float4*)((char*)Gout + ((size_t)gw << 7) + f8 * 16) = o.f4;
    }
}

// Final: y = D*Ahat(G3) + u2*c0 + u1*c1 + u0*c2 + b3; store Y fp32;
// Out = y @ Wout + bout.
__global__ __launch_bounds__(256) void agg_final_k(
    const __half* __restrict__ G, const float* __restrict__ dinv,
    const int* __restrict__ rowptr, const int* __restrict__ coff,
    const float* __restrict__ u0, const float* __restrict__ u1,
    const float* __restrict__ u2, const float* __restrict__ cbuf,
    const float* __restrict__ b3, const float* __restrict__ Wout,
    const float* __restrict__ bout, float* __restrict__ Y,
    float* __restrict__ Out, int N) {
    int gw = (blockIdx.x * 256 + threadIdx.x) >> 6;
    int lane = threadIdx.x & 63;
    if (gw >= N) return;
    gw = __builtin_amdgcn_readfirstlane(gw);
    int grp = lane >> 3;
    int f8 = lane & 7;
    int s = rowptr[gw], e = rowptr[gw + 1];
    float r[8];
    agg_node8(G, coff, s, e, gw << 7, grp, f8, r);
    float d = dinv[gw];
    float u0v = u0[gw], u1v = u1[gw], u2v = u2[gw];
    const float* c0 = cbuf;
    const float* c1 = cbuf + 64;
    const float* c2 = cbuf + 128;
    float v[8];
#pragma unroll
    for (int half = 0; half < 2; half++) {
        int o4 = f8 * 8 + half * 4;
        float4 c0v = *(const float4*)(c0 + o4);
        float4 c1v = *(const float4*)(c1 + o4);
        float4 c2v = *(const float4*)(c2 + o4);
        float4 b3v = *(const float4*)(b3 + o4);
        v[half * 4 + 0] = r[half * 4 + 0] * d + u2v * c0v.x + u1v * c1v.x + u0v * c2v.x + b3v.x;
        v[half * 4 + 1] = r[half * 4 + 1] * d + u2v * c0v.y + u1v * c1v.y + u0v * c2v.y + b3v.y;
        v[half * 4 + 2] = r[half * 4 + 2] * d + u2v * c0v.z + u1v * c1v.z + u0v * c2v.z + b3v.z;
        v[half * 4 + 3] = r[half * 4 + 3] * d + u2v * c0v.w + u1v * c1v.w + u0v * c2v.w + b3v.w;
    }
    if (grp == 0) {
        float* o = Y + (size_t)gw * EMB + f8 * 8;
        *(float4*)o = make_float4(v[0], v[1], v[2], v[3]);
        *(float4*)(o + 4) = make_float4(v[4], v[5], v[6], v[7]);
    }
    float4 w0v = *(const float4*)(Wout + f8 * 8);
    float4 w1v = *(const float4*)(Wout + f8 * 8 + 4);
    float p = v[0] * w0v.x + v[1] * w0v.y + v[2] * w0v.z + v[3] * w0v.w +
              v[4] * w1v.x + v[5] * w1v.y + v[6] * w1v.z + v[7] * w1v.w;
    p += __shfl_xor(p, 1, 8);
    p += __shfl_xor(p, 2, 8);
    p += __shfl_xor(p, 4, 8);
    if (lane == 0) Out[gw] = p + bout[0];
}

// ---------------- launch ----------------

extern "C" void kernel_launch(void* const* d_in, const int* in_sizes, int n_in,
                              void* d_out, int out_size, void* d_ws, size_t ws_size,
                              hipStream_t stream) {
    const float* x    = (const float*)d_in[0];
    const int*   ei   = (const int*)d_in[1];
    const float* W0   = (const float*)d_in[3];
    const float* b0   = (const float*)d_in[4];
    const float* W1   = (const float*)d_in[5];
    const float* b1   = (const float*)d_in[6];
    const float* W2   = (const float*)d_in[7];
    const float* b2   = (const float*)d_in[8];
    const float* W3   = (const float*)d_in[9];
    const float* b3   = (const float*)d_in[10];
    const float* Wout = (const float*)d_in[11];
    const float* bout = (const float*)d_in[12];

    const int N = in_sizes[0] / FEAT;      // 100000
    const int E = in_sizes[1] / 2;         // 3200000
    const int* srcp = ei;                  // edge_index[0]
    const int* dstp = ei + E;              // edge_index[1]
    const int nbin = (N + BINSIZE - 1) / BINSIZE;   // 391

    // workspace layout (floats; regions padded to 64 for float4 alignment)
    const int NP = ((N + 64) + 63) / 64 * 64;   // holds N+1
    float* dinv  = (float*)d_ws;
    int* rowptr  = (int*)(dinv + NP);
    int* bincnt  = rowptr + NP;
    int* binptr  = bincnt + 1024;
    int* bincur  = binptr + 1024;
    int* col     = bincur + 1024;
    float* u0    = (float*)(col + ((E + 63) / 64) * 64);
    float* u1    = u0 + NP;
    float* u2    = u1 + NP;
    float* Wc    = u2 + NP;                // 128x64 = 8192 floats
    float* cbuf  = Wc + 8192;              // 192 floats (c0,c1,c2)
    float* gbase = cbuf + 256;
    int* ebuf    = (int*)gbase;            // aliased: dead before gemm0
    __half* Gbuf0 = (__half*)gbase;        // fp16 G ping (12.8MB)
    __half* Gbuf1 = Gbuf0 + (size_t)N * EMB;  // fp16 G pong (12.8MB)
    float* wa    = (float*)(Gbuf1 + (size_t)N * EMB);  // svec scratch
    float* wb    = wa + NP;

    float* Out = (float*)d_out;
    float* Y   = Out + N;

    const int ntile = (N + 63) / 64;               // 1563
    const int gemm_grid = (ntile < 768) ? ntile : 768;
    const int agg_blocks = (N + 3) / 4;            // 25000 exact-grid
    const int svec_blocks = (N + 255) / 256;       // 391
    const int nchunk = (E + CHUNK - 1) / CHUNK;

    // --- CSR build ---
    hipMemsetAsync(bincnt, 0, 1024 * sizeof(int), stream);
    bin_count_k<<<nchunk, 256, 0, stream>>>(dstp, bincnt, E);
    binscan_k<<<1, 512, 0, stream>>>(bincnt, binptr, bincur, nbin, E);
    bin_edges_k<<<nchunk, 256, 0, stream>>>(srcp, dstp, bincur, ebuf, E);
    build_csr_k<<<nbin, 256, 0, stream>>>(ebuf, binptr, rowptr, dinv, col, N, E, nbin);

    // --- the single GEMM: G0 = D * (x @ Wc)?  No: gemm needs Wc. ---
    // Wc is produced by smallmats; but gemm0 uses Wc so smallmats must
    // precede gemm0. Keep smallmats here (small, after CSR) and use the
    // svecs as the huge->huge separators.
    smallmats_k<<<1, 256, 0, stream>>>(W0, W1, W2, W3, b0, b1, b2, Wc, cbuf);
    gemm_scale_k<FEAT><<<gemm_grid, 256, 0, stream>>>(x, Wc, dinv, Gbuf0, N, ntile);

    // --- S applications, interleaved with svec separators ---
    // u0 = S*1, u1 = S^2*1, u2 = S^3*1  (w0 = D*1 = dinv)
    svec_k<<<svec_blocks, 256, 0, stream>>>(dinv, dinv, rowptr, col, u0, wa, N);
    agg_mid_k<<<agg_blocks, 256, 0, stream>>>(Gbuf0, dinv, rowptr, col, Gbuf1, N);
    svec_k<<<svec_blocks, 256, 0, stream>>>(wa, dinv, rowptr, col, u1, wb, N);
    agg_mid_k<<<agg_blocks, 256, 0, stream>>>(Gbuf1, dinv, rowptr, col, Gbuf0, N);
    svec_k<<<svec_blocks, 256, 0, stream>>>(wb, dinv, rowptr, col, u2, wa, N);
    agg_mid_k<<<agg_blocks, 256, 0, stream>>>(Gbuf0, dinv, rowptr, col, Gbuf1, N);
    // small separator before the final huge dispatch: re-run binscan-free
    // cheap kernel? Use svec on wa -> wb (dead result) would waste ~6us;
    // instead rely on final being the LAST dispatch (tail drain overlaps
    // nothing downstream anyway).
    agg_final_k<<<agg_blocks, 256, 0, stream>>>(Gbuf1, dinv, rowptr, col,
                                                u0, u1, u2, cbuf, b3, Wout, bout,
                                                Y, Out, N);
}